// Round 1
// baseline (3103.159 us; speedup 1.0000x reference)
//
#include <hip/hip_runtime.h>

#define DIM 2048
#define NH 16
#define HD 128
#define BB 2
#define LL 2048
#define MROWS (BB * LL)   // 4096

// ---------------------------------------------------------------------------
// GEMM: Y = X @ W, fp32 row-major. BM=BN=64, BK=16, 256 threads, 4x4/thread.
// M is implicit via grid.y*64; K, N passed (K=2048; N in {2048,128}).
// ---------------------------------------------------------------------------
__global__ __launch_bounds__(256) void gemm_f32(const float* __restrict__ X,
                                                const float* __restrict__ W,
                                                float* __restrict__ Y,
                                                int K, int N) {
    __shared__ float As[16][64];   // transposed: As[k][m]
    __shared__ float Bs[16][64];   // Bs[k][n]
    const int tid = threadIdx.x;
    const int tx = tid & 15, ty = tid >> 4;
    const int m0 = blockIdx.y * 64, n0 = blockIdx.x * 64;

    float acc[4][4] = {};
    const int arow = tid >> 2, ac4 = tid & 3;    // X tile: 64 rows x 4 float4
    const int brow = tid >> 4, bc4 = tid & 15;   // W tile: 16 rows x 16 float4

    for (int k0 = 0; k0 < K; k0 += 16) {
        __syncthreads();
        float4 xa = *reinterpret_cast<const float4*>(
            &X[(size_t)(m0 + arow) * K + k0 + ac4 * 4]);
        As[ac4 * 4 + 0][arow] = xa.x;
        As[ac4 * 4 + 1][arow] = xa.y;
        As[ac4 * 4 + 2][arow] = xa.z;
        As[ac4 * 4 + 3][arow] = xa.w;
        *reinterpret_cast<float4*>(&Bs[brow][bc4 * 4]) =
            *reinterpret_cast<const float4*>(
                &W[(size_t)(k0 + brow) * N + n0 + bc4 * 4]);
        __syncthreads();
#pragma unroll
        for (int kk = 0; kk < 16; ++kk) {
            float4 a = *reinterpret_cast<const float4*>(&As[kk][ty * 4]);
            float4 b = *reinterpret_cast<const float4*>(&Bs[kk][tx * 4]);
            float av[4] = {a.x, a.y, a.z, a.w};
            float bv[4] = {b.x, b.y, b.z, b.w};
#pragma unroll
            for (int i = 0; i < 4; ++i)
#pragma unroll
                for (int j = 0; j < 4; ++j) acc[i][j] += av[i] * bv[j];
        }
    }
#pragma unroll
    for (int i = 0; i < 4; ++i) {
        float4 o = {acc[i][0], acc[i][1], acc[i][2], acc[i][3]};
        *reinterpret_cast<float4*>(
            &Y[(size_t)(m0 + ty * 4 + i) * N + n0 + tx * 4]) = o;
    }
}

// ---------------------------------------------------------------------------
// RoPE + RMSNorm, in place. One wave per 128-wide row; lane d holds (d, d+64).
// ref: x1,x2 = split(x,2,-1); out = [x1*cos + x2*sin, -x1*sin + x2*cos]
// then x * rsqrt(mean(x^2) + 1e-6) over the 128-dim.
// ---------------------------------------------------------------------------
__global__ __launch_bounds__(256) void rope_rms(float* __restrict__ t,
                                                const float* __restrict__ cosb,
                                                const float* __restrict__ sinb,
                                                int heads, int nrows) {
    int row = blockIdx.x * 4 + (threadIdx.x >> 6);
    int lane = threadIdx.x & 63;
    if (row >= nrows) return;
    int l = (row / heads) & (LL - 1);   // position index
    float* p = t + (size_t)row * HD;
    float x1 = p[lane];
    float x2 = p[lane + 64];
    float c = cosb[l * 64 + lane];
    float s = sinb[l * 64 + lane];
    float o1 = x1 * c + x2 * s;
    float o2 = -x1 * s + x2 * c;
    float ss = o1 * o1 + o2 * o2;
#pragma unroll
    for (int off = 32; off > 0; off >>= 1) ss += __shfl_xor(ss, off);
    float r = rsqrtf(ss * (1.0f / 128.0f) + 1e-6f);
    p[lane] = o1 * r;
    p[lane + 64] = o2 * r;
}

// ---------------------------------------------------------------------------
// Flash-style causal MQA attention, fp32. BQ=BK=32, 256 threads.
// Q layout (B,L,H,D); K/V layout (B,L,D); O layout (B,L,H,D).
// ---------------------------------------------------------------------------
#define BQ 32
#define BK 32

__global__ __launch_bounds__(256) void flash_attn(const float* __restrict__ Q,
                                                  const float* __restrict__ Kb,
                                                  const float* __restrict__ Vb,
                                                  float* __restrict__ O) {
    __shared__ float Qs[BQ][132];
    __shared__ float Ks[BK][132];
    __shared__ float Vs[BK][132];
    __shared__ float Ps[BQ][36];
    __shared__ float m_row[BQ], l_row[BQ], a_row[BQ];

    const int tid = threadIdx.x;
    const int bh = blockIdx.y;
    const int b = bh >> 4, h = bh & 15;
    const int q0 = blockIdx.x * BQ;

    // Q tile load: 32 rows x 128 floats, row stride NH*HD
    {
        const float* qbase = Q + ((size_t)(b * LL + q0) * NH + h) * HD;
#pragma unroll
        for (int rep = 0; rep < 4; ++rep) {
            int f = tid + rep * 256;
            int r = f >> 5, c4 = f & 31;
            float4 v = *reinterpret_cast<const float4*>(
                qbase + (size_t)r * (NH * HD) + c4 * 4);
            *reinterpret_cast<float4*>(&Qs[r][c4 * 4]) = v;
        }
        if (tid < BQ) { m_row[tid] = -1e30f; l_row[tid] = 0.0f; }
    }

    const int irow = tid >> 3, jgrp = tid & 7;   // score mapping
    const int i2 = irow, dgrp = jgrp;            // O mapping (16 cols/thread)
    float o[16];
#pragma unroll
    for (int u = 0; u < 16; ++u) o[u] = 0.0f;

    const float scale = 0.08838834764831845f;    // 1/sqrt(128)
    const int ntiles = blockIdx.x + 1;           // causal

    for (int kt = 0; kt < ntiles; ++kt) {
        const int k0 = kt * BK;
        __syncthreads();   // prev phase C done with Vs/Ps
        {
            const float* kbase = Kb + (size_t)(b * LL + k0) * HD;
            const float* vbase = Vb + (size_t)(b * LL + k0) * HD;
#pragma unroll
            for (int rep = 0; rep < 4; ++rep) {
                int f = tid + rep * 256;
                int r = f >> 5, c4 = f & 31;
                float4 kv = *reinterpret_cast<const float4*>(
                    kbase + (size_t)r * HD + c4 * 4);
                *reinterpret_cast<float4*>(&Ks[r][c4 * 4]) = kv;
                float4 vv = *reinterpret_cast<const float4*>(
                    vbase + (size_t)r * HD + c4 * 4);
                *reinterpret_cast<float4*>(&Vs[r][c4 * 4]) = vv;
            }
        }
        __syncthreads();

        // phase A: S[irow][jgrp*4 .. +3]
        float s[4] = {0.f, 0.f, 0.f, 0.f};
        for (int d4 = 0; d4 < 32; ++d4) {
            float4 q4 = *reinterpret_cast<const float4*>(&Qs[irow][d4 * 4]);
#pragma unroll
            for (int jj = 0; jj < 4; ++jj) {
                float4 k4 = *reinterpret_cast<const float4*>(
                    &Ks[jgrp * 4 + jj][d4 * 4]);
                s[jj] += q4.x * k4.x + q4.y * k4.y + q4.z * k4.z + q4.w * k4.w;
            }
        }
        const int qi = q0 + irow;
#pragma unroll
        for (int jj = 0; jj < 4; ++jj) {
            int kj = k0 + jgrp * 4 + jj;
            s[jj] = (kj <= qi) ? s[jj] * scale : -1e30f;
        }

        // phase B: online softmax (8 lanes per row, consecutive -> shfl_xor)
        float lmax = fmaxf(fmaxf(s[0], s[1]), fmaxf(s[2], s[3]));
#pragma unroll
        for (int off = 1; off < 8; off <<= 1)
            lmax = fmaxf(lmax, __shfl_xor(lmax, off));
        float m_old = m_row[irow];
        float m_new = fmaxf(m_old, lmax);
        float p[4];
        float psum = 0.0f;
#pragma unroll
        for (int jj = 0; jj < 4; ++jj) {
            p[jj] = __expf(s[jj] - m_new);
            psum += p[jj];
        }
#pragma unroll
        for (int off = 1; off < 8; off <<= 1) psum += __shfl_xor(psum, off);
        if (jgrp == 0) {
            float alpha = __expf(m_old - m_new);
            l_row[irow] = l_row[irow] * alpha + psum;
            m_row[irow] = m_new;
            a_row[irow] = alpha;
        }
#pragma unroll
        for (int jj = 0; jj < 4; ++jj) Ps[irow][jgrp * 4 + jj] = p[jj];
        __syncthreads();

        // phase C: O = O*alpha + P @ V  (thread: row i2, cols dgrp*16..+15)
        float alpha = a_row[i2];
#pragma unroll
        for (int u = 0; u < 16; ++u) o[u] *= alpha;
        for (int j = 0; j < BK; ++j) {
            float pv = Ps[i2][j];
#pragma unroll
            for (int c = 0; c < 4; ++c) {
                float4 v4 = *reinterpret_cast<const float4*>(
                    &Vs[j][dgrp * 16 + c * 4]);
                o[c * 4 + 0] += pv * v4.x;
                o[c * 4 + 1] += pv * v4.y;
                o[c * 4 + 2] += pv * v4.z;
                o[c * 4 + 3] += pv * v4.w;
            }
        }
    }

    // epilogue: normalize and store
    float inv_l = 1.0f / l_row[i2];
    float* obase = O + ((size_t)(b * LL + q0 + i2) * NH + h) * HD + dgrp * 16;
#pragma unroll
    for (int c = 0; c < 4; ++c) {
        float4 ov = {o[c * 4 + 0] * inv_l, o[c * 4 + 1] * inv_l,
                     o[c * 4 + 2] * inv_l, o[c * 4 + 3] * inv_l};
        *reinterpret_cast<float4*>(obase + c * 4) = ov;
    }
}

// ---------------------------------------------------------------------------
extern "C" void kernel_launch(void* const* d_in, const int* in_sizes, int n_in,
                              void* d_out, int out_size, void* d_ws,
                              size_t ws_size, hipStream_t stream) {
    const float* x    = (const float*)d_in[0];
    const float* cosb = (const float*)d_in[1];
    const float* sinb = (const float*)d_in[2];
    const float* Wq   = (const float*)d_in[3];
    const float* Wk   = (const float*)d_in[4];
    const float* Wv   = (const float*)d_in[5];
    const float* Wo   = (const float*)d_in[6];
    float* out = (float*)d_out;

    float* q  = (float*)d_ws;                    // MROWS*DIM
    float* k  = q + (size_t)MROWS * DIM;         // MROWS*HD
    float* v  = k + (size_t)MROWS * HD;          // MROWS*HD
    float* ao = v + (size_t)MROWS * HD;          // MROWS*DIM

    // projections
    gemm_f32<<<dim3(DIM / 64, MROWS / 64), 256, 0, stream>>>(x, Wq, q, DIM, DIM);
    gemm_f32<<<dim3(HD / 64, MROWS / 64), 256, 0, stream>>>(x, Wk, k, DIM, HD);
    gemm_f32<<<dim3(HD / 64, MROWS / 64), 256, 0, stream>>>(x, Wv, v, DIM, HD);

    // RoPE + RMSNorm (q: 16 heads/row-group; k: single head)
    rope_rms<<<dim3(MROWS * NH / 4), 256, 0, stream>>>(q, cosb, sinb, NH,
                                                       MROWS * NH);
    rope_rms<<<dim3(MROWS / 4), 256, 0, stream>>>(k, cosb, sinb, 1, MROWS);

    // causal MQA attention
    flash_attn<<<dim3(LL / BQ, BB * NH), 256, 0, stream>>>(q, k, v, ao);

    // output projection
    gemm_f32<<<dim3(DIM / 64, MROWS / 64), 256, 0, stream>>>(ao, Wo, out, DIM,
                                                             DIM);
}

// Round 2
// 1457.605 us; speedup vs baseline: 2.1289x; 2.1289x over previous
//
#include <hip/hip_runtime.h>

#define DIM 2048
#define NH 16
#define HD 128
#define BB 2
#define LL 2048
#define MROWS (BB * LL)   // 4096

typedef __attribute__((ext_vector_type(8))) short short8;
typedef __attribute__((ext_vector_type(4))) float floatx4;

__device__ inline ushort f2bf(float f) {
    union { float f; unsigned u; } v; v.f = f;
    unsigned r = v.u + 0x7FFFu + ((v.u >> 16) & 1u);
    return (ushort)(r >> 16);
}

// ---------------------------------------------------------------------------
// GEMM: Y = X @ W, fp32 row-major. BM=BN=64, BK=16, 256 threads, 4x4/thread.
// ---------------------------------------------------------------------------
__global__ __launch_bounds__(256) void gemm_f32(const float* __restrict__ X,
                                                const float* __restrict__ W,
                                                float* __restrict__ Y,
                                                int K, int N) {
    __shared__ float As[16][64];
    __shared__ float Bs[16][64];
    const int tid = threadIdx.x;
    const int tx = tid & 15, ty = tid >> 4;
    const int m0 = blockIdx.y * 64, n0 = blockIdx.x * 64;

    float acc[4][4] = {};
    const int arow = tid >> 2, ac4 = tid & 3;
    const int brow = tid >> 4, bc4 = tid & 15;

    for (int k0 = 0; k0 < K; k0 += 16) {
        __syncthreads();
        float4 xa = *reinterpret_cast<const float4*>(
            &X[(size_t)(m0 + arow) * K + k0 + ac4 * 4]);
        As[ac4 * 4 + 0][arow] = xa.x;
        As[ac4 * 4 + 1][arow] = xa.y;
        As[ac4 * 4 + 2][arow] = xa.z;
        As[ac4 * 4 + 3][arow] = xa.w;
        *reinterpret_cast<float4*>(&Bs[brow][bc4 * 4]) =
            *reinterpret_cast<const float4*>(
                &W[(size_t)(k0 + brow) * N + n0 + bc4 * 4]);
        __syncthreads();
#pragma unroll
        for (int kk = 0; kk < 16; ++kk) {
            float4 a = *reinterpret_cast<const float4*>(&As[kk][ty * 4]);
            float4 b = *reinterpret_cast<const float4*>(&Bs[kk][tx * 4]);
            float av[4] = {a.x, a.y, a.z, a.w};
            float bv[4] = {b.x, b.y, b.z, b.w};
#pragma unroll
            for (int i = 0; i < 4; ++i)
#pragma unroll
                for (int j = 0; j < 4; ++j) acc[i][j] += av[i] * bv[j];
        }
    }
#pragma unroll
    for (int i = 0; i < 4; ++i) {
        float4 o = {acc[i][0], acc[i][1], acc[i][2], acc[i][3]};
        *reinterpret_cast<float4*>(
            &Y[(size_t)(m0 + ty * 4 + i) * N + n0 + tx * 4]) = o;
    }
}

// ---------------------------------------------------------------------------
// RoPE + RMSNorm: fp32 in -> bf16 out (round-to-nearest). One wave per row.
// ---------------------------------------------------------------------------
__global__ __launch_bounds__(256) void rope_rms_bf16(const float* __restrict__ in,
                                                     ushort* __restrict__ outb,
                                                     const float* __restrict__ cosb,
                                                     const float* __restrict__ sinb,
                                                     int heads, int nrows) {
    int row = blockIdx.x * 4 + (threadIdx.x >> 6);
    int lane = threadIdx.x & 63;
    if (row >= nrows) return;
    int l = (row / heads) & (LL - 1);
    const float* p = in + (size_t)row * HD;
    float x1 = p[lane];
    float x2 = p[lane + 64];
    float c = cosb[l * 64 + lane];
    float s = sinb[l * 64 + lane];
    float o1 = x1 * c + x2 * s;
    float o2 = -x1 * s + x2 * c;
    float ss = o1 * o1 + o2 * o2;
#pragma unroll
    for (int off = 32; off > 0; off >>= 1) ss += __shfl_xor(ss, off);
    float r = rsqrtf(ss * (1.0f / 128.0f) + 1e-6f);
    outb[(size_t)row * HD + lane] = f2bf(o1 * r);
    outb[(size_t)row * HD + lane + 64] = f2bf(o2 * r);
}

// ---------------------------------------------------------------------------
// V transpose + bf16 convert: v (B,L,128) f32 -> vt (B,128,L) bf16.
// 64x64 tiles via LDS. grid (LL/64, 2, BB), 256 threads.
// ---------------------------------------------------------------------------
__global__ __launch_bounds__(256) void vtrans(const float* __restrict__ v,
                                              ushort* __restrict__ vt) {
    __shared__ ushort T[64][72];
    const int l0 = blockIdx.x * 64, d0 = blockIdx.y * 64, b = blockIdx.z;
    const int tid = threadIdx.x;
#pragma unroll
    for (int rep = 0; rep < 4; ++rep) {
        int idx = tid + rep * 256;
        int r = idx >> 4, c4 = idx & 15;
        float4 f = *reinterpret_cast<const float4*>(
            v + (size_t)(b * LL + l0 + r) * HD + d0 + c4 * 4);
        T[r][c4 * 4 + 0] = f2bf(f.x);
        T[r][c4 * 4 + 1] = f2bf(f.y);
        T[r][c4 * 4 + 2] = f2bf(f.z);
        T[r][c4 * 4 + 3] = f2bf(f.w);
    }
    __syncthreads();
#pragma unroll
    for (int rep = 0; rep < 4; ++rep) {
        int idx = tid + rep * 256;
        int dr = idx >> 4, lc4 = idx & 15;
        uint a0 = (uint)T[lc4 * 4 + 0][dr] | ((uint)T[lc4 * 4 + 1][dr] << 16);
        uint a1 = (uint)T[lc4 * 4 + 2][dr] | ((uint)T[lc4 * 4 + 3][dr] << 16);
        uint2 val = {a0, a1};
        *reinterpret_cast<uint2*>(
            vt + (size_t)(b * HD + d0 + dr) * LL + l0 + lc4 * 4) = val;
    }
}

// ---------------------------------------------------------------------------
// Flash-style causal MQA attention with bf16 MFMA 16x16x32.
// BQ=BK=64, 256 threads (4 waves), wave w owns Q rows w*16..w*16+15.
// qb (B,L,H,D) bf16; kb (B,L,D) bf16; vt (B,D,L) bf16; ao (B,L,H,D) f32.
// ---------------------------------------------------------------------------
__global__ __launch_bounds__(256) void flash_mfma(const ushort* __restrict__ qb,
                                                  const ushort* __restrict__ kb,
                                                  const ushort* __restrict__ vt,
                                                  float* __restrict__ ao) {
    __shared__ ushort Qs[64][136];    // 17408 B, rows 272B (16B-aligned)
    __shared__ ushort Ks[64][136];    // 17408 B
    __shared__ ushort VTs[128][72];   // 18432 B, rows 144B
    __shared__ ushort Ps[4][16][72];  // 9216 B, per-wave P buffer

    const int tid = threadIdx.x;
    const int w = tid >> 6, lane = tid & 63;
    const int col = lane & 15, quad = lane >> 4;
    const int qt = blockIdx.x, bh = blockIdx.y;
    const int b = bh >> 4, h = bh & 15;
    const int q0 = qt * 64;
    const float scale = 0.08838834764831845f;  // 1/sqrt(128)

    // ---- stage Q tile (64 rows x 128 bf16) ----
#pragma unroll
    for (int rep = 0; rep < 4; ++rep) {
        int idx = tid + rep * 256;
        int r = idx >> 4, c8 = idx & 15;
        float4 src = *reinterpret_cast<const float4*>(
            qb + ((size_t)(b * LL + q0 + r) * NH + h) * HD + c8 * 8);
        *reinterpret_cast<float4*>(&Qs[r][c8 * 8]) = src;
    }
    __syncthreads();

    // A-frags for Q (reused across all K-tiles)
    short8 aq[4];
#pragma unroll
    for (int kc = 0; kc < 4; ++kc)
        aq[kc] = *reinterpret_cast<const short8*>(
            &Qs[w * 16 + col][kc * 32 + quad * 8]);

    float mrow[4], lrow[4];
    floatx4 oacc[8];
#pragma unroll
    for (int rr = 0; rr < 4; ++rr) { mrow[rr] = -1e30f; lrow[rr] = 0.0f; }
#pragma unroll
    for (int dt = 0; dt < 8; ++dt) oacc[dt] = (floatx4){0.f, 0.f, 0.f, 0.f};

    const int ntiles = qt + 1;
    for (int kt = 0; kt < ntiles; ++kt) {
        const int k0 = kt * 64;
        __syncthreads();  // previous iteration done with Ks/VTs
        // ---- stage K tile (64 x 128 bf16) ----
#pragma unroll
        for (int rep = 0; rep < 4; ++rep) {
            int idx = tid + rep * 256;
            int r = idx >> 4, c8 = idx & 15;
            float4 src = *reinterpret_cast<const float4*>(
                kb + (size_t)(b * LL + k0 + r) * HD + c8 * 8);
            *reinterpret_cast<float4*>(&Ks[r][c8 * 8]) = src;
        }
        // ---- stage V^T tile (128 x 64 bf16) ----
#pragma unroll
        for (int rep = 0; rep < 4; ++rep) {
            int idx = tid + rep * 256;
            int d = idx >> 3, k8 = idx & 7;
            float4 src = *reinterpret_cast<const float4*>(
                vt + (size_t)(b * HD + d) * LL + k0 + k8 * 8);
            *reinterpret_cast<float4*>(&VTs[d][k8 * 8]) = src;
        }
        __syncthreads();

        // ---- S = Q K^T  (4 tiles of 16x16, K-dim 128) ----
        floatx4 sacc[4];
#pragma unroll
        for (int nt = 0; nt < 4; ++nt) sacc[nt] = (floatx4){0.f, 0.f, 0.f, 0.f};
#pragma unroll
        for (int nt = 0; nt < 4; ++nt) {
#pragma unroll
            for (int kc = 0; kc < 4; ++kc) {
                short8 bk = *reinterpret_cast<const short8*>(
                    &Ks[nt * 16 + col][kc * 32 + quad * 8]);
                sacc[nt] = __builtin_amdgcn_mfma_f32_16x16x32_bf16(
                    aq[kc], bk, sacc[nt], 0, 0, 0);
            }
        }

        // ---- scale + causal mask + online softmax ----
        float cmax[4] = {-1e30f, -1e30f, -1e30f, -1e30f};
#pragma unroll
        for (int nt = 0; nt < 4; ++nt) {
            int kj = k0 + nt * 16 + col;
#pragma unroll
            for (int rr = 0; rr < 4; ++rr) {
                int qi = q0 + w * 16 + quad * 4 + rr;
                float s = sacc[nt][rr] * scale;
                s = (kj <= qi) ? s : -1e30f;
                sacc[nt][rr] = s;
                cmax[rr] = fmaxf(cmax[rr], s);
            }
        }
#pragma unroll
        for (int off = 1; off < 16; off <<= 1)
#pragma unroll
            for (int rr = 0; rr < 4; ++rr)
                cmax[rr] = fmaxf(cmax[rr], __shfl_xor(cmax[rr], off));
        float alpha[4];
#pragma unroll
        for (int rr = 0; rr < 4; ++rr) {
            float mn = fmaxf(mrow[rr], cmax[rr]);
            alpha[rr] = __expf(mrow[rr] - mn);
            mrow[rr] = mn;
        }
        float psum[4] = {0.f, 0.f, 0.f, 0.f};
#pragma unroll
        for (int nt = 0; nt < 4; ++nt)
#pragma unroll
            for (int rr = 0; rr < 4; ++rr) {
                float p = __expf(sacc[nt][rr] - mrow[rr]);
                sacc[nt][rr] = p;
                psum[rr] += p;
            }
#pragma unroll
        for (int off = 1; off < 16; off <<= 1)
#pragma unroll
            for (int rr = 0; rr < 4; ++rr) psum[rr] += __shfl_xor(psum[rr], off);
#pragma unroll
        for (int rr = 0; rr < 4; ++rr)
            lrow[rr] = lrow[rr] * alpha[rr] + psum[rr];
#pragma unroll
        for (int dt = 0; dt < 8; ++dt)
#pragma unroll
            for (int rr = 0; rr < 4; ++rr) oacc[dt][rr] *= alpha[rr];

        // ---- P: C-layout -> LDS -> A-layout (per-wave buffer, no barrier) ----
#pragma unroll
        for (int nt = 0; nt < 4; ++nt)
#pragma unroll
            for (int rr = 0; rr < 4; ++rr)
                Ps[w][quad * 4 + rr][nt * 16 + col] = f2bf(sacc[nt][rr]);
        asm volatile("s_waitcnt lgkmcnt(0)" ::: "memory");

        // ---- O += P V  (BK=64 -> 2 K-chunks of 32) ----
#pragma unroll
        for (int kt2 = 0; kt2 < 2; ++kt2) {
            short8 ap = *reinterpret_cast<const short8*>(
                &Ps[w][col][kt2 * 32 + quad * 8]);
#pragma unroll
            for (int dt = 0; dt < 8; ++dt) {
                short8 bv = *reinterpret_cast<const short8*>(
                    &VTs[dt * 16 + col][kt2 * 32 + quad * 8]);
                oacc[dt] = __builtin_amdgcn_mfma_f32_16x16x32_bf16(
                    ap, bv, oacc[dt], 0, 0, 0);
            }
        }
    }

    // ---- epilogue: normalize, store fp32 ----
    float inv[4];
#pragma unroll
    for (int rr = 0; rr < 4; ++rr) inv[rr] = 1.0f / lrow[rr];
#pragma unroll
    for (int dt = 0; dt < 8; ++dt)
#pragma unroll
        for (int rr = 0; rr < 4; ++rr)
            ao[((size_t)(b * LL + q0 + w * 16 + quad * 4 + rr) * NH + h) * HD +
               dt * 16 + col] = oacc[dt][rr] * inv[rr];
}

// ---------------------------------------------------------------------------
extern "C" void kernel_launch(void* const* d_in, const int* in_sizes, int n_in,
                              void* d_out, int out_size, void* d_ws,
                              size_t ws_size, hipStream_t stream) {
    const float* x    = (const float*)d_in[0];
    const float* cosb = (const float*)d_in[1];
    const float* sinb = (const float*)d_in[2];
    const float* Wq   = (const float*)d_in[3];
    const float* Wk   = (const float*)d_in[4];
    const float* Wv   = (const float*)d_in[5];
    const float* Wo   = (const float*)d_in[6];
    float* out = (float*)d_out;

    float* q  = (float*)d_ws;                       // MROWS*DIM f32 (later ao)
    float* k  = q + (size_t)MROWS * DIM;            // MROWS*HD f32
    float* v  = k + (size_t)MROWS * HD;             // MROWS*HD f32
    ushort* qb = (ushort*)(v + (size_t)MROWS * HD); // MROWS*DIM bf16
    ushort* kb = qb + (size_t)MROWS * DIM;          // MROWS*HD bf16
    ushort* vt = kb + (size_t)MROWS * HD;           // MROWS*HD bf16 (B,D,L)
    float* ao = q;  // q fp32 is dead after rope_rms_bf16 -> reuse for attn out

    // projections (fp32 this round)
    gemm_f32<<<dim3(DIM / 64, MROWS / 64), 256, 0, stream>>>(x, Wq, q, DIM, DIM);
    gemm_f32<<<dim3(HD / 64, MROWS / 64), 256, 0, stream>>>(x, Wk, k, DIM, HD);
    gemm_f32<<<dim3(HD / 64, MROWS / 64), 256, 0, stream>>>(x, Wv, v, DIM, HD);

    // RoPE + RMSNorm -> bf16
    rope_rms_bf16<<<dim3(MROWS * NH / 4), 256, 0, stream>>>(q, qb, cosb, sinb,
                                                            NH, MROWS * NH);
    rope_rms_bf16<<<dim3(MROWS / 4), 256, 0, stream>>>(k, kb, cosb, sinb, 1,
                                                       MROWS);
    // V -> bf16 transposed (B,D,L)
    vtrans<<<dim3(LL / 64, 2, BB), 256, 0, stream>>>(v, vt);

    // causal MQA attention, bf16 MFMA
    flash_mfma<<<dim3(LL / 64, BB * NH), 256, 0, stream>>>(qb, kb, vt, ao);

    // output projection
    gemm_f32<<<dim3(DIM / 64, MROWS / 64), 256, 0, stream>>>(ao, Wo, out, DIM,
                                                             DIM);
}

// Round 3
// 481.026 us; speedup vs baseline: 6.4511x; 3.0302x over previous
//
#include <hip/hip_runtime.h>

#define DIM 2048
#define NH 16
#define HD 128
#define BB 2
#define LL 2048
#define MROWS (BB * LL)   // 4096

typedef __attribute__((ext_vector_type(8))) short short8;
typedef __attribute__((ext_vector_type(4))) float floatx4;

__device__ inline ushort f2bf(float f) {
    union { float f; unsigned u; } v; v.f = f;
    unsigned r = v.u + 0x7FFFu + ((v.u >> 16) & 1u);
    return (ushort)(r >> 16);
}

#define GL16(g, l)                                                         \
    __builtin_amdgcn_global_load_lds(                                      \
        (const __attribute__((address_space(1))) unsigned int*)(g),        \
        (__attribute__((address_space(3))) unsigned int*)(l), 16, 0, 0)

// ---------------------------------------------------------------------------
// elementwise f32 -> bf16 (8 elems/thread)
// ---------------------------------------------------------------------------
__global__ __launch_bounds__(256) void conv_bf16(const float* __restrict__ in,
                                                 ushort* __restrict__ out) {
    size_t i = ((size_t)blockIdx.x * 256 + threadIdx.x) * 8;
    float4 a = *reinterpret_cast<const float4*>(in + i);
    float4 b = *reinterpret_cast<const float4*>(in + i + 4);
    ushort o[8] = {f2bf(a.x), f2bf(a.y), f2bf(a.z), f2bf(a.w),
                   f2bf(b.x), f2bf(b.y), f2bf(b.z), f2bf(b.w)};
    *reinterpret_cast<uint4*>(out + i) = *reinterpret_cast<uint4*>(o);
}

// ---------------------------------------------------------------------------
// transpose + convert: in f32 (R,C) -> out bf16 (C,R). 64x64 tiles.
// grid (C/64, R/64).
// ---------------------------------------------------------------------------
__global__ __launch_bounds__(256) void trans_bf16(const float* __restrict__ in,
                                                  ushort* __restrict__ out,
                                                  int in_ld, int out_ld) {
    __shared__ ushort T[64][72];
    const int c0 = blockIdx.x * 64, r0 = blockIdx.y * 64;
    const int tid = threadIdx.x;
#pragma unroll
    for (int rep = 0; rep < 4; ++rep) {
        int idx = tid + rep * 256;
        int r = idx >> 4, c4 = idx & 15;
        float4 f = *reinterpret_cast<const float4*>(
            in + (size_t)(r0 + r) * in_ld + c0 + c4 * 4);
        T[r][c4 * 4 + 0] = f2bf(f.x);
        T[r][c4 * 4 + 1] = f2bf(f.y);
        T[r][c4 * 4 + 2] = f2bf(f.z);
        T[r][c4 * 4 + 3] = f2bf(f.w);
    }
    __syncthreads();
#pragma unroll
    for (int rep = 0; rep < 4; ++rep) {
        int idx = tid + rep * 256;
        int cr = idx >> 4, rc4 = idx & 15;
        uint a0 = (uint)T[rc4 * 4 + 0][cr] | ((uint)T[rc4 * 4 + 1][cr] << 16);
        uint a1 = (uint)T[rc4 * 4 + 2][cr] | ((uint)T[rc4 * 4 + 3][cr] << 16);
        uint2 val = {a0, a1};
        *reinterpret_cast<uint2*>(
            out + (size_t)(c0 + cr) * out_ld + r0 + rc4 * 4) = val;
    }
}

// ---------------------------------------------------------------------------
// bf16 MFMA GEMM (m97 structure): Y = A @ Bt^T.
// A bf16 (M,K) row-major, Bt bf16 (N,K) row-major, Y f32 (M,N).
// BM=BN=128, BK=32, 256 threads (4 waves, each 64x64).
// ---------------------------------------------------------------------------
__global__ __launch_bounds__(256) void gemm_bf16(const ushort* __restrict__ A,
                                                 const ushort* __restrict__ Bt,
                                                 float* __restrict__ Y,
                                                 int K, int N) {
    __shared__ ushort As[128 * 32];   // 8 KB, row-major (row, k)
    __shared__ ushort Bs[128 * 32];   // 8 KB
    const int tid = threadIdx.x;
    const int lane = tid & 63;
    const int w = tid >> 6;
    const int col = lane & 15, quad = lane >> 4;
    const int m0 = blockIdx.y * 128, n0 = blockIdx.x * 128;
    const int wm = (w >> 1) * 64, wn = (w & 1) * 64;

    floatx4 acc[4][4];
#pragma unroll
    for (int mt = 0; mt < 4; ++mt)
#pragma unroll
        for (int nt = 0; nt < 4; ++nt) acc[mt][nt] = (floatx4){0.f, 0.f, 0.f, 0.f};

    const int r = tid >> 2;   // 0..63
    const int c = tid & 3;    // 16B chunk within BK row

    for (int k0 = 0; k0 < K; k0 += 32) {
        __syncthreads();
        GL16(A + (size_t)(m0 + r) * K + k0 + c * 8, As + (size_t)tid * 8);
        GL16(A + (size_t)(m0 + 64 + r) * K + k0 + c * 8,
             As + (size_t)(tid + 256) * 8);
        GL16(Bt + (size_t)(n0 + r) * K + k0 + c * 8, Bs + (size_t)tid * 8);
        GL16(Bt + (size_t)(n0 + 64 + r) * K + k0 + c * 8,
             Bs + (size_t)(tid + 256) * 8);
        __syncthreads();

        short8 af[4], bf[4];
#pragma unroll
        for (int mt = 0; mt < 4; ++mt)
            af[mt] = *reinterpret_cast<const short8*>(
                &As[(wm + mt * 16 + col) * 32 + quad * 8]);
#pragma unroll
        for (int nt = 0; nt < 4; ++nt)
            bf[nt] = *reinterpret_cast<const short8*>(
                &Bs[(wn + nt * 16 + col) * 32 + quad * 8]);
#pragma unroll
        for (int mt = 0; mt < 4; ++mt)
#pragma unroll
            for (int nt = 0; nt < 4; ++nt)
                acc[mt][nt] = __builtin_amdgcn_mfma_f32_16x16x32_bf16(
                    af[mt], bf[nt], acc[mt][nt], 0, 0, 0);
    }

#pragma unroll
    for (int mt = 0; mt < 4; ++mt)
#pragma unroll
        for (int nt = 0; nt < 4; ++nt)
#pragma unroll
            for (int rr = 0; rr < 4; ++rr)
                Y[(size_t)(m0 + wm + mt * 16 + quad * 4 + rr) * N + n0 + wn +
                  nt * 16 + col] = acc[mt][nt][rr];
}

// ---------------------------------------------------------------------------
// RoPE + RMSNorm: fp32 in (row stride in_ld) -> bf16 out (row stride HD).
// ---------------------------------------------------------------------------
__global__ __launch_bounds__(256) void rope_rms_bf16(const float* __restrict__ in,
                                                     ushort* __restrict__ outb,
                                                     const float* __restrict__ cosb,
                                                     const float* __restrict__ sinb,
                                                     int heads, int nrows,
                                                     int in_ld) {
    int row = blockIdx.x * 4 + (threadIdx.x >> 6);
    int lane = threadIdx.x & 63;
    if (row >= nrows) return;
    int l = (row / heads) & (LL - 1);
    const float* p = in + (size_t)row * in_ld;
    float x1 = p[lane];
    float x2 = p[lane + 64];
    float c = cosb[l * 64 + lane];
    float s = sinb[l * 64 + lane];
    float o1 = x1 * c + x2 * s;
    float o2 = -x1 * s + x2 * c;
    float ss = o1 * o1 + o2 * o2;
#pragma unroll
    for (int off = 32; off > 0; off >>= 1) ss += __shfl_xor(ss, off);
    float r = rsqrtf(ss * (1.0f / 128.0f) + 1e-6f);
    outb[(size_t)row * HD + lane] = f2bf(o1 * r);
    outb[(size_t)row * HD + lane + 64] = f2bf(o2 * r);
}

// ---------------------------------------------------------------------------
// V transpose + bf16: in f32 (B*L, in_ld) cols 0..127 -> vt (B,128,L) bf16.
// grid (LL/64, 2, BB).
// ---------------------------------------------------------------------------
__global__ __launch_bounds__(256) void vtrans(const float* __restrict__ v,
                                              ushort* __restrict__ vt,
                                              int in_ld) {
    __shared__ ushort T[64][72];
    const int l0 = blockIdx.x * 64, d0 = blockIdx.y * 64, b = blockIdx.z;
    const int tid = threadIdx.x;
#pragma unroll
    for (int rep = 0; rep < 4; ++rep) {
        int idx = tid + rep * 256;
        int r = idx >> 4, c4 = idx & 15;
        float4 f = *reinterpret_cast<const float4*>(
            v + (size_t)(b * LL + l0 + r) * in_ld + d0 + c4 * 4);
        T[r][c4 * 4 + 0] = f2bf(f.x);
        T[r][c4 * 4 + 1] = f2bf(f.y);
        T[r][c4 * 4 + 2] = f2bf(f.z);
        T[r][c4 * 4 + 3] = f2bf(f.w);
    }
    __syncthreads();
#pragma unroll
    for (int rep = 0; rep < 4; ++rep) {
        int idx = tid + rep * 256;
        int dr = idx >> 4, lc4 = idx & 15;
        uint a0 = (uint)T[lc4 * 4 + 0][dr] | ((uint)T[lc4 * 4 + 1][dr] << 16);
        uint a1 = (uint)T[lc4 * 4 + 2][dr] | ((uint)T[lc4 * 4 + 3][dr] << 16);
        uint2 val = {a0, a1};
        *reinterpret_cast<uint2*>(
            vt + (size_t)(b * HD + d0 + dr) * LL + l0 + lc4 * 4) = val;
    }
}

// ---------------------------------------------------------------------------
// Flash-style causal MQA attention with bf16 MFMA 16x16x32.
// BQ=BK=64, 256 threads (4 waves). Output bf16 (B,L,H,D).
// ---------------------------------------------------------------------------
__global__ __launch_bounds__(256) void flash_mfma(const ushort* __restrict__ qb,
                                                  const ushort* __restrict__ kb,
                                                  const ushort* __restrict__ vt,
                                                  ushort* __restrict__ aob) {
    __shared__ ushort Qs[64][136];
    __shared__ ushort Ks[64][136];
    __shared__ ushort VTs[128][72];
    __shared__ ushort Ps[4][16][72];

    const int tid = threadIdx.x;
    const int w = tid >> 6, lane = tid & 63;
    const int col = lane & 15, quad = lane >> 4;
    const int qt = blockIdx.x, bh = blockIdx.y;
    const int b = bh >> 4, h = bh & 15;
    const int q0 = qt * 64;
    const float scale = 0.08838834764831845f;  // 1/sqrt(128)

#pragma unroll
    for (int rep = 0; rep < 4; ++rep) {
        int idx = tid + rep * 256;
        int r = idx >> 4, c8 = idx & 15;
        float4 src = *reinterpret_cast<const float4*>(
            qb + ((size_t)(b * LL + q0 + r) * NH + h) * HD + c8 * 8);
        *reinterpret_cast<float4*>(&Qs[r][c8 * 8]) = src;
    }
    __syncthreads();

    short8 aq[4];
#pragma unroll
    for (int kc = 0; kc < 4; ++kc)
        aq[kc] = *reinterpret_cast<const short8*>(
            &Qs[w * 16 + col][kc * 32 + quad * 8]);

    float mrow[4], lrow[4];
    floatx4 oacc[8];
#pragma unroll
    for (int rr = 0; rr < 4; ++rr) { mrow[rr] = -1e30f; lrow[rr] = 0.0f; }
#pragma unroll
    for (int dt = 0; dt < 8; ++dt) oacc[dt] = (floatx4){0.f, 0.f, 0.f, 0.f};

    const int ntiles = qt + 1;
    for (int kt = 0; kt < ntiles; ++kt) {
        const int k0 = kt * 64;
        __syncthreads();
#pragma unroll
        for (int rep = 0; rep < 4; ++rep) {
            int idx = tid + rep * 256;
            int r = idx >> 4, c8 = idx & 15;
            float4 src = *reinterpret_cast<const float4*>(
                kb + (size_t)(b * LL + k0 + r) * HD + c8 * 8);
            *reinterpret_cast<float4*>(&Ks[r][c8 * 8]) = src;
        }
#pragma unroll
        for (int rep = 0; rep < 4; ++rep) {
            int idx = tid + rep * 256;
            int d = idx >> 3, k8 = idx & 7;
            float4 src = *reinterpret_cast<const float4*>(
                vt + (size_t)(b * HD + d) * LL + k0 + k8 * 8);
            *reinterpret_cast<float4*>(&VTs[d][k8 * 8]) = src;
        }
        __syncthreads();

        floatx4 sacc[4];
#pragma unroll
        for (int nt = 0; nt < 4; ++nt) sacc[nt] = (floatx4){0.f, 0.f, 0.f, 0.f};
#pragma unroll
        for (int nt = 0; nt < 4; ++nt) {
#pragma unroll
            for (int kc = 0; kc < 4; ++kc) {
                short8 bk = *reinterpret_cast<const short8*>(
                    &Ks[nt * 16 + col][kc * 32 + quad * 8]);
                sacc[nt] = __builtin_amdgcn_mfma_f32_16x16x32_bf16(
                    aq[kc], bk, sacc[nt], 0, 0, 0);
            }
        }

        float cmax[4] = {-1e30f, -1e30f, -1e30f, -1e30f};
#pragma unroll
        for (int nt = 0; nt < 4; ++nt) {
            int kj = k0 + nt * 16 + col;
#pragma unroll
            for (int rr = 0; rr < 4; ++rr) {
                int qi = q0 + w * 16 + quad * 4 + rr;
                float s = sacc[nt][rr] * scale;
                s = (kj <= qi) ? s : -1e30f;
                sacc[nt][rr] = s;
                cmax[rr] = fmaxf(cmax[rr], s);
            }
        }
#pragma unroll
        for (int off = 1; off < 16; off <<= 1)
#pragma unroll
            for (int rr = 0; rr < 4; ++rr)
                cmax[rr] = fmaxf(cmax[rr], __shfl_xor(cmax[rr], off));
        float alpha[4];
#pragma unroll
        for (int rr = 0; rr < 4; ++rr) {
            float mn = fmaxf(mrow[rr], cmax[rr]);
            alpha[rr] = __expf(mrow[rr] - mn);
            mrow[rr] = mn;
        }
        float psum[4] = {0.f, 0.f, 0.f, 0.f};
#pragma unroll
        for (int nt = 0; nt < 4; ++nt)
#pragma unroll
            for (int rr = 0; rr < 4; ++rr) {
                float p = __expf(sacc[nt][rr] - mrow[rr]);
                sacc[nt][rr] = p;
                psum[rr] += p;
            }
#pragma unroll
        for (int off = 1; off < 16; off <<= 1)
#pragma unroll
            for (int rr = 0; rr < 4; ++rr) psum[rr] += __shfl_xor(psum[rr], off);
#pragma unroll
        for (int rr = 0; rr < 4; ++rr)
            lrow[rr] = lrow[rr] * alpha[rr] + psum[rr];
#pragma unroll
        for (int dt = 0; dt < 8; ++dt)
#pragma unroll
            for (int rr = 0; rr < 4; ++rr) oacc[dt][rr] *= alpha[rr];

#pragma unroll
        for (int nt = 0; nt < 4; ++nt)
#pragma unroll
            for (int rr = 0; rr < 4; ++rr)
                Ps[w][quad * 4 + rr][nt * 16 + col] = f2bf(sacc[nt][rr]);
        asm volatile("s_waitcnt lgkmcnt(0)" ::: "memory");

#pragma unroll
        for (int kt2 = 0; kt2 < 2; ++kt2) {
            short8 ap = *reinterpret_cast<const short8*>(
                &Ps[w][col][kt2 * 32 + quad * 8]);
#pragma unroll
            for (int dt = 0; dt < 8; ++dt) {
                short8 bv = *reinterpret_cast<const short8*>(
                    &VTs[dt * 16 + col][kt2 * 32 + quad * 8]);
                oacc[dt] = __builtin_amdgcn_mfma_f32_16x16x32_bf16(
                    ap, bv, oacc[dt], 0, 0, 0);
            }
        }
    }

    float inv[4];
#pragma unroll
    for (int rr = 0; rr < 4; ++rr) inv[rr] = 1.0f / lrow[rr];
#pragma unroll
    for (int dt = 0; dt < 8; ++dt)
#pragma unroll
        for (int rr = 0; rr < 4; ++rr)
            aob[((size_t)(b * LL + q0 + w * 16 + quad * 4 + rr) * NH + h) * HD +
                dt * 16 + col] = f2bf(oacc[dt][rr] * inv[rr]);
}

// ---------------------------------------------------------------------------
extern "C" void kernel_launch(void* const* d_in, const int* in_sizes, int n_in,
                              void* d_out, int out_size, void* d_ws,
                              size_t ws_size, hipStream_t stream) {
    const float* x    = (const float*)d_in[0];
    const float* cosb = (const float*)d_in[1];
    const float* sinb = (const float*)d_in[2];
    const float* Wq   = (const float*)d_in[3];
    const float* Wk   = (const float*)d_in[4];
    const float* Wv   = (const float*)d_in[5];
    const float* Wo   = (const float*)d_in[6];
    float* out = (float*)d_out;

    float* q    = (float*)d_ws;                        // M*DIM f32
    float* kv   = q + (size_t)MROWS * DIM;             // M*256 f32
    ushort* xb  = (ushort*)(kv + (size_t)MROWS * 256); // M*DIM bf16
    ushort* qb  = xb + (size_t)MROWS * DIM;            // M*DIM bf16
    ushort* kb  = qb + (size_t)MROWS * DIM;            // M*HD bf16
    ushort* vt  = kb + (size_t)MROWS * HD;             // M*HD bf16 (B,D,L)
    ushort* aob = vt + (size_t)MROWS * HD;             // M*DIM bf16
    ushort* Wqt  = aob + (size_t)MROWS * DIM;          // DIM*DIM bf16 (N,K)
    ushort* Wkvt = Wqt + (size_t)DIM * DIM;            // 256*DIM bf16
    ushort* Wot  = Wkvt + (size_t)256 * DIM;           // DIM*DIM bf16

    // convert inputs to bf16 (x elementwise; weights transposed to (N,K))
    conv_bf16<<<dim3(MROWS * DIM / (256 * 8)), 256, 0, stream>>>(x, xb);
    trans_bf16<<<dim3(32, 32), 256, 0, stream>>>(Wq, Wqt, DIM, DIM);
    trans_bf16<<<dim3(2, 32), 256, 0, stream>>>(Wk, Wkvt, HD, DIM);
    trans_bf16<<<dim3(2, 32), 256, 0, stream>>>(Wv, Wkvt + (size_t)HD * DIM,
                                                HD, DIM);
    trans_bf16<<<dim3(32, 32), 256, 0, stream>>>(Wo, Wot, DIM, DIM);

    // projections (bf16 MFMA)
    gemm_bf16<<<dim3(DIM / 128, MROWS / 128), 256, 0, stream>>>(xb, Wqt, q,
                                                                DIM, DIM);
    gemm_bf16<<<dim3(256 / 128, MROWS / 128), 256, 0, stream>>>(xb, Wkvt, kv,
                                                                DIM, 256);

    // RoPE + RMSNorm -> bf16
    rope_rms_bf16<<<dim3(MROWS * NH / 4), 256, 0, stream>>>(
        q, qb, cosb, sinb, NH, MROWS * NH, HD);
    rope_rms_bf16<<<dim3(MROWS / 4), 256, 0, stream>>>(
        kv, kb, cosb, sinb, 1, MROWS, 256);
    // V -> bf16 transposed (B,D,L); V occupies cols 128..255 of kv
    vtrans<<<dim3(LL / 64, 2, BB), 256, 0, stream>>>(kv + HD, vt, 256);

    // causal MQA attention, bf16 MFMA, bf16 out
    flash_mfma<<<dim3(LL / 64, BB * NH), 256, 0, stream>>>(qb, kb, vt, aob);

    // output projection
    gemm_bf16<<<dim3(DIM / 128, MROWS / 128), 256, 0, stream>>>(aob, Wot, out,
                                                                DIM, DIM);
}

// Round 4
// 380.767 us; speedup vs baseline: 8.1498x; 1.2633x over previous
//
#include <hip/hip_runtime.h>

#define DIM 2048
#define NH 16
#define HD 128
#define BB 2
#define LL 2048
#define MROWS (BB * LL)   // 4096

typedef __attribute__((ext_vector_type(8))) short short8;
typedef __attribute__((ext_vector_type(4))) float floatx4;

__device__ inline ushort f2bf(float f) {
    union { float f; unsigned u; } v; v.f = f;
    unsigned r = v.u + 0x7FFFu + ((v.u >> 16) & 1u);
    return (ushort)(r >> 16);
}

#define GL16(g, l)                                                         \
    __builtin_amdgcn_global_load_lds(                                      \
        (const __attribute__((address_space(1))) unsigned int*)(g),        \
        (__attribute__((address_space(3))) unsigned int*)(l), 16, 0, 0)

// ---------------------------------------------------------------------------
// elementwise f32 -> bf16 (8 elems/thread)
// ---------------------------------------------------------------------------
__global__ __launch_bounds__(256) void conv_bf16(const float* __restrict__ in,
                                                 ushort* __restrict__ out) {
    size_t i = ((size_t)blockIdx.x * 256 + threadIdx.x) * 8;
    float4 a = *reinterpret_cast<const float4*>(in + i);
    float4 b = *reinterpret_cast<const float4*>(in + i + 4);
    ushort o[8] = {f2bf(a.x), f2bf(a.y), f2bf(a.z), f2bf(a.w),
                   f2bf(b.x), f2bf(b.y), f2bf(b.z), f2bf(b.w)};
    *reinterpret_cast<uint4*>(out + i) = *reinterpret_cast<uint4*>(o);
}

// ---------------------------------------------------------------------------
// transpose + convert: in f32 (R,C) -> out bf16 (C,R). 64x64 tiles.
// ---------------------------------------------------------------------------
__global__ __launch_bounds__(256) void trans_bf16(const float* __restrict__ in,
                                                  ushort* __restrict__ out,
                                                  int in_ld, int out_ld) {
    __shared__ ushort T[64][72];
    const int c0 = blockIdx.x * 64, r0 = blockIdx.y * 64;
    const int tid = threadIdx.x;
#pragma unroll
    for (int rep = 0; rep < 4; ++rep) {
        int idx = tid + rep * 256;
        int r = idx >> 4, c4 = idx & 15;
        float4 f = *reinterpret_cast<const float4*>(
            in + (size_t)(r0 + r) * in_ld + c0 + c4 * 4);
        T[r][c4 * 4 + 0] = f2bf(f.x);
        T[r][c4 * 4 + 1] = f2bf(f.y);
        T[r][c4 * 4 + 2] = f2bf(f.z);
        T[r][c4 * 4 + 3] = f2bf(f.w);
    }
    __syncthreads();
#pragma unroll
    for (int rep = 0; rep < 4; ++rep) {
        int idx = tid + rep * 256;
        int cr = idx >> 4, rc4 = idx & 15;
        uint a0 = (uint)T[rc4 * 4 + 0][cr] | ((uint)T[rc4 * 4 + 1][cr] << 16);
        uint a1 = (uint)T[rc4 * 4 + 2][cr] | ((uint)T[rc4 * 4 + 3][cr] << 16);
        uint2 val = {a0, a1};
        *reinterpret_cast<uint2*>(
            out + (size_t)(c0 + cr) * out_ld + r0 + rc4 * 4) = val;
    }
}

// ---------------------------------------------------------------------------
// bf16 MFMA GEMM: Y = A @ Bt^T. BM=BN=128, BK=32, 256 threads.
// ---------------------------------------------------------------------------
__global__ __launch_bounds__(256) void gemm_bf16(const ushort* __restrict__ A,
                                                 const ushort* __restrict__ Bt,
                                                 float* __restrict__ Y,
                                                 int K, int N) {
    __shared__ ushort As[128 * 32];
    __shared__ ushort Bs[128 * 32];
    const int tid = threadIdx.x;
    const int lane = tid & 63;
    const int w = tid >> 6;
    const int col = lane & 15, quad = lane >> 4;
    const int m0 = blockIdx.y * 128, n0 = blockIdx.x * 128;
    const int wm = (w >> 1) * 64, wn = (w & 1) * 64;

    floatx4 acc[4][4];
#pragma unroll
    for (int mt = 0; mt < 4; ++mt)
#pragma unroll
        for (int nt = 0; nt < 4; ++nt) acc[mt][nt] = (floatx4){0.f, 0.f, 0.f, 0.f};

    const int r = tid >> 2;
    const int c = tid & 3;

    for (int k0 = 0; k0 < K; k0 += 32) {
        __syncthreads();
        GL16(A + (size_t)(m0 + r) * K + k0 + c * 8, As + (size_t)tid * 8);
        GL16(A + (size_t)(m0 + 64 + r) * K + k0 + c * 8,
             As + (size_t)(tid + 256) * 8);
        GL16(Bt + (size_t)(n0 + r) * K + k0 + c * 8, Bs + (size_t)tid * 8);
        GL16(Bt + (size_t)(n0 + 64 + r) * K + k0 + c * 8,
             Bs + (size_t)(tid + 256) * 8);
        __syncthreads();

        short8 af[4], bf[4];
#pragma unroll
        for (int mt = 0; mt < 4; ++mt)
            af[mt] = *reinterpret_cast<const short8*>(
                &As[(wm + mt * 16 + col) * 32 + quad * 8]);
#pragma unroll
        for (int nt = 0; nt < 4; ++nt)
            bf[nt] = *reinterpret_cast<const short8*>(
                &Bs[(wn + nt * 16 + col) * 32 + quad * 8]);
#pragma unroll
        for (int mt = 0; mt < 4; ++mt)
#pragma unroll
            for (int nt = 0; nt < 4; ++nt)
                acc[mt][nt] = __builtin_amdgcn_mfma_f32_16x16x32_bf16(
                    af[mt], bf[nt], acc[mt][nt], 0, 0, 0);
    }

#pragma unroll
    for (int mt = 0; mt < 4; ++mt)
#pragma unroll
        for (int nt = 0; nt < 4; ++nt)
#pragma unroll
            for (int rr = 0; rr < 4; ++rr)
                Y[(size_t)(m0 + wm + mt * 16 + quad * 4 + rr) * N + n0 + wn +
                  nt * 16 + col] = acc[mt][nt][rr];
}

// ---------------------------------------------------------------------------
// bf16 MFMA GEMM, small-N variant: BM=BN=64, BK=64, 256 threads.
// Wave w computes rows w*16..w*16+15 x all 64 cols.
// ---------------------------------------------------------------------------
__global__ __launch_bounds__(256) void gemm_bf16_64(const ushort* __restrict__ A,
                                                    const ushort* __restrict__ Bt,
                                                    float* __restrict__ Y,
                                                    int K, int N) {
    __shared__ ushort As[64 * 64];   // 8 KB
    __shared__ ushort Bs[64 * 64];
    const int tid = threadIdx.x;
    const int lane = tid & 63;
    const int w = tid >> 6;
    const int col = lane & 15, quad = lane >> 4;
    const int m0 = blockIdx.y * 64, n0 = blockIdx.x * 64;

    floatx4 acc[4];
#pragma unroll
    for (int nt = 0; nt < 4; ++nt) acc[nt] = (floatx4){0.f, 0.f, 0.f, 0.f};

    const int r = tid >> 3;   // 0..31
    const int c = tid & 7;    // 16B chunk in 128B row

    for (int k0 = 0; k0 < K; k0 += 64) {
        __syncthreads();
        GL16(A + (size_t)(m0 + r) * K + k0 + c * 8, As + (size_t)tid * 8);
        GL16(A + (size_t)(m0 + 32 + r) * K + k0 + c * 8,
             As + (size_t)(tid + 256) * 8);
        GL16(Bt + (size_t)(n0 + r) * K + k0 + c * 8, Bs + (size_t)tid * 8);
        GL16(Bt + (size_t)(n0 + 32 + r) * K + k0 + c * 8,
             Bs + (size_t)(tid + 256) * 8);
        __syncthreads();

#pragma unroll
        for (int kc = 0; kc < 2; ++kc) {
            short8 af = *reinterpret_cast<const short8*>(
                &As[(w * 16 + col) * 64 + kc * 32 + quad * 8]);
#pragma unroll
            for (int nt = 0; nt < 4; ++nt) {
                short8 bf = *reinterpret_cast<const short8*>(
                    &Bs[(nt * 16 + col) * 64 + kc * 32 + quad * 8]);
                acc[nt] = __builtin_amdgcn_mfma_f32_16x16x32_bf16(
                    af, bf, acc[nt], 0, 0, 0);
            }
        }
    }

#pragma unroll
    for (int nt = 0; nt < 4; ++nt)
#pragma unroll
        for (int rr = 0; rr < 4; ++rr)
            Y[(size_t)(m0 + w * 16 + quad * 4 + rr) * N + n0 + nt * 16 + col] =
                acc[nt][rr];
}

// ---------------------------------------------------------------------------
// RoPE + RMSNorm: fp32 in (row stride in_ld) -> bf16 out (row stride HD).
// ---------------------------------------------------------------------------
__global__ __launch_bounds__(256) void rope_rms_bf16(const float* __restrict__ in,
                                                     ushort* __restrict__ outb,
                                                     const float* __restrict__ cosb,
                                                     const float* __restrict__ sinb,
                                                     int heads, int nrows,
                                                     int in_ld) {
    int row = blockIdx.x * 4 + (threadIdx.x >> 6);
    int lane = threadIdx.x & 63;
    if (row >= nrows) return;
    int l = (row / heads) & (LL - 1);
    const float* p = in + (size_t)row * in_ld;
    float x1 = p[lane];
    float x2 = p[lane + 64];
    float c = cosb[l * 64 + lane];
    float s = sinb[l * 64 + lane];
    float o1 = x1 * c + x2 * s;
    float o2 = -x1 * s + x2 * c;
    float ss = o1 * o1 + o2 * o2;
#pragma unroll
    for (int off = 32; off > 0; off >>= 1) ss += __shfl_xor(ss, off);
    float r = rsqrtf(ss * (1.0f / 128.0f) + 1e-6f);
    outb[(size_t)row * HD + lane] = f2bf(o1 * r);
    outb[(size_t)row * HD + lane + 64] = f2bf(o2 * r);
}

// ---------------------------------------------------------------------------
// V transpose + bf16: in f32 (B*L, in_ld) cols 0..127 -> vt (B,128,L) bf16.
// ---------------------------------------------------------------------------
__global__ __launch_bounds__(256) void vtrans(const float* __restrict__ v,
                                              ushort* __restrict__ vt,
                                              int in_ld) {
    __shared__ ushort T[64][72];
    const int l0 = blockIdx.x * 64, d0 = blockIdx.y * 64, b = blockIdx.z;
    const int tid = threadIdx.x;
#pragma unroll
    for (int rep = 0; rep < 4; ++rep) {
        int idx = tid + rep * 256;
        int r = idx >> 4, c4 = idx & 15;
        float4 f = *reinterpret_cast<const float4*>(
            v + (size_t)(b * LL + l0 + r) * in_ld + d0 + c4 * 4);
        T[r][c4 * 4 + 0] = f2bf(f.x);
        T[r][c4 * 4 + 1] = f2bf(f.y);
        T[r][c4 * 4 + 2] = f2bf(f.z);
        T[r][c4 * 4 + 3] = f2bf(f.w);
    }
    __syncthreads();
#pragma unroll
    for (int rep = 0; rep < 4; ++rep) {
        int idx = tid + rep * 256;
        int dr = idx >> 4, lc4 = idx & 15;
        uint a0 = (uint)T[lc4 * 4 + 0][dr] | ((uint)T[lc4 * 4 + 1][dr] << 16);
        uint a1 = (uint)T[lc4 * 4 + 2][dr] | ((uint)T[lc4 * 4 + 3][dr] << 16);
        uint2 val = {a0, a1};
        *reinterpret_cast<uint2*>(
            vt + (size_t)(b * HD + d0 + dr) * LL + l0 + lc4 * 4) = val;
    }
}

// ---------------------------------------------------------------------------
// Flash-style causal MQA attention, bf16 MFMA 16x16x32, LOAD-BALANCED:
// block pairIdx processes q-strips {pairIdx, 31-pairIdx} -> 33 k-tiles each.
// 256 threads (4 waves), wave w owns Q rows w*16..w*16+15 of the strip.
// ---------------------------------------------------------------------------
__global__ __launch_bounds__(256) void flash_mfma(const ushort* __restrict__ qb,
                                                  const ushort* __restrict__ kb,
                                                  const ushort* __restrict__ vt,
                                                  ushort* __restrict__ aob) {
    __shared__ ushort Ks[64][136];    // 17408 B
    __shared__ ushort VTs[128][72];   // 18432 B
    __shared__ ushort Ps[4][16][72];  // 9216 B

    const int tid = threadIdx.x;
    const int w = tid >> 6, lane = tid & 63;
    const int col = lane & 15, quad = lane >> 4;
    const int pairIdx = blockIdx.x, bh = blockIdx.y;
    const int b = bh >> 4, h = bh & 15;
    const float scale = 0.08838834764831845f;  // 1/sqrt(128)

    for (int sp = 0; sp < 2; ++sp) {
        const int qt = sp ? (31 - pairIdx) : pairIdx;
        const int q0 = qt * 64;

        // ---- A-frags for Q: direct global -> reg (16B per lane per kc) ----
        const ushort* qrow =
            qb + ((size_t)(b * LL + q0 + w * 16 + col) * NH + h) * HD;
        short8 aq[4];
#pragma unroll
        for (int kc = 0; kc < 4; ++kc)
            aq[kc] = *reinterpret_cast<const short8*>(qrow + kc * 32 + quad * 8);

        float mrow[4], lrow[4];
        floatx4 oacc[8];
#pragma unroll
        for (int rr = 0; rr < 4; ++rr) { mrow[rr] = -1e30f; lrow[rr] = 0.0f; }
#pragma unroll
        for (int dt = 0; dt < 8; ++dt) oacc[dt] = (floatx4){0.f, 0.f, 0.f, 0.f};

        const int ntiles = qt + 1;
        for (int kt = 0; kt < ntiles; ++kt) {
            const int k0 = kt * 64;
            __syncthreads();
#pragma unroll
            for (int rep = 0; rep < 4; ++rep) {
                int idx = tid + rep * 256;
                int r = idx >> 4, c8 = idx & 15;
                float4 src = *reinterpret_cast<const float4*>(
                    kb + (size_t)(b * LL + k0 + r) * HD + c8 * 8);
                *reinterpret_cast<float4*>(&Ks[r][c8 * 8]) = src;
            }
#pragma unroll
            for (int rep = 0; rep < 4; ++rep) {
                int idx = tid + rep * 256;
                int d = idx >> 3, k8 = idx & 7;
                float4 src = *reinterpret_cast<const float4*>(
                    vt + (size_t)(b * HD + d) * LL + k0 + k8 * 8);
                *reinterpret_cast<float4*>(&VTs[d][k8 * 8]) = src;
            }
            __syncthreads();

            // S = Q K^T
            floatx4 sacc[4];
#pragma unroll
            for (int nt = 0; nt < 4; ++nt)
                sacc[nt] = (floatx4){0.f, 0.f, 0.f, 0.f};
#pragma unroll
            for (int nt = 0; nt < 4; ++nt) {
#pragma unroll
                for (int kc = 0; kc < 4; ++kc) {
                    short8 bk = *reinterpret_cast<const short8*>(
                        &Ks[nt * 16 + col][kc * 32 + quad * 8]);
                    sacc[nt] = __builtin_amdgcn_mfma_f32_16x16x32_bf16(
                        aq[kc], bk, sacc[nt], 0, 0, 0);
                }
            }

            // scale + causal mask + running max
            float cmax[4] = {-1e30f, -1e30f, -1e30f, -1e30f};
#pragma unroll
            for (int nt = 0; nt < 4; ++nt) {
                int kj = k0 + nt * 16 + col;
#pragma unroll
                for (int rr = 0; rr < 4; ++rr) {
                    int qi = q0 + w * 16 + quad * 4 + rr;
                    float s = sacc[nt][rr] * scale;
                    s = (kj <= qi) ? s : -1e30f;
                    sacc[nt][rr] = s;
                    cmax[rr] = fmaxf(cmax[rr], s);
                }
            }
#pragma unroll
            for (int off = 1; off < 16; off <<= 1)
#pragma unroll
                for (int rr = 0; rr < 4; ++rr)
                    cmax[rr] = fmaxf(cmax[rr], __shfl_xor(cmax[rr], off));
            float alpha[4];
#pragma unroll
            for (int rr = 0; rr < 4; ++rr) {
                float mn = fmaxf(mrow[rr], cmax[rr]);
                alpha[rr] = __expf(mrow[rr] - mn);
                mrow[rr] = mn;
            }
            // exp + per-lane l accumulation (no per-tile cross-lane reduce)
            float psum[4] = {0.f, 0.f, 0.f, 0.f};
#pragma unroll
            for (int nt = 0; nt < 4; ++nt)
#pragma unroll
                for (int rr = 0; rr < 4; ++rr) {
                    float p = __expf(sacc[nt][rr] - mrow[rr]);
                    sacc[nt][rr] = p;
                    psum[rr] += p;
                }
#pragma unroll
            for (int rr = 0; rr < 4; ++rr)
                lrow[rr] = lrow[rr] * alpha[rr] + psum[rr];
#pragma unroll
            for (int dt = 0; dt < 8; ++dt)
#pragma unroll
                for (int rr = 0; rr < 4; ++rr) oacc[dt][rr] *= alpha[rr];

            // P: C-layout -> LDS -> A-layout (per-wave buffer)
#pragma unroll
            for (int nt = 0; nt < 4; ++nt)
#pragma unroll
                for (int rr = 0; rr < 4; ++rr)
                    Ps[w][quad * 4 + rr][nt * 16 + col] = f2bf(sacc[nt][rr]);
            asm volatile("s_waitcnt lgkmcnt(0)" ::: "memory");

            // O += P V
#pragma unroll
            for (int kt2 = 0; kt2 < 2; ++kt2) {
                short8 ap = *reinterpret_cast<const short8*>(
                    &Ps[w][col][kt2 * 32 + quad * 8]);
#pragma unroll
                for (int dt = 0; dt < 8; ++dt) {
                    short8 bv = *reinterpret_cast<const short8*>(
                        &VTs[dt * 16 + col][kt2 * 32 + quad * 8]);
                    oacc[dt] = __builtin_amdgcn_mfma_f32_16x16x32_bf16(
                        ap, bv, oacc[dt], 0, 0, 0);
                }
            }
        }

        // epilogue: reduce per-lane l across the 16 row lanes, store bf16
#pragma unroll
        for (int off = 1; off < 16; off <<= 1)
#pragma unroll
            for (int rr = 0; rr < 4; ++rr)
                lrow[rr] += __shfl_xor(lrow[rr], off);
        float inv[4];
#pragma unroll
        for (int rr = 0; rr < 4; ++rr) inv[rr] = 1.0f / lrow[rr];
#pragma unroll
        for (int dt = 0; dt < 8; ++dt)
#pragma unroll
            for (int rr = 0; rr < 4; ++rr)
                aob[((size_t)(b * LL + q0 + w * 16 + quad * 4 + rr) * NH + h) *
                        HD + dt * 16 + col] = f2bf(oacc[dt][rr] * inv[rr]);
    }
}

// ---------------------------------------------------------------------------
extern "C" void kernel_launch(void* const* d_in, const int* in_sizes, int n_in,
                              void* d_out, int out_size, void* d_ws,
                              size_t ws_size, hipStream_t stream) {
    const float* x    = (const float*)d_in[0];
    const float* cosb = (const float*)d_in[1];
    const float* sinb = (const float*)d_in[2];
    const float* Wq   = (const float*)d_in[3];
    const float* Wk   = (const float*)d_in[4];
    const float* Wv   = (const float*)d_in[5];
    const float* Wo   = (const float*)d_in[6];
    float* out = (float*)d_out;

    float* q    = (float*)d_ws;                        // M*DIM f32
    float* kv   = q + (size_t)MROWS * DIM;             // M*256 f32
    ushort* xb  = (ushort*)(kv + (size_t)MROWS * 256); // M*DIM bf16
    ushort* qb  = xb + (size_t)MROWS * DIM;            // M*DIM bf16
    ushort* kb  = qb + (size_t)MROWS * DIM;            // M*HD bf16
    ushort* vt  = kb + (size_t)MROWS * HD;             // M*HD bf16 (B,D,L)
    ushort* aob = vt + (size_t)MROWS * HD;             // M*DIM bf16
    ushort* Wqt  = aob + (size_t)MROWS * DIM;          // DIM*DIM bf16 (N,K)
    ushort* Wkvt = Wqt + (size_t)DIM * DIM;            // 256*DIM bf16
    ushort* Wot  = Wkvt + (size_t)256 * DIM;           // DIM*DIM bf16

    conv_bf16<<<dim3(MROWS * DIM / (256 * 8)), 256, 0, stream>>>(x, xb);
    trans_bf16<<<dim3(32, 32), 256, 0, stream>>>(Wq, Wqt, DIM, DIM);
    trans_bf16<<<dim3(2, 32), 256, 0, stream>>>(Wk, Wkvt, HD, DIM);
    trans_bf16<<<dim3(2, 32), 256, 0, stream>>>(Wv, Wkvt + (size_t)HD * DIM,
                                                HD, DIM);
    trans_bf16<<<dim3(32, 32), 256, 0, stream>>>(Wo, Wot, DIM, DIM);

    // projections
    gemm_bf16<<<dim3(DIM / 128, MROWS / 128), 256, 0, stream>>>(xb, Wqt, q,
                                                                DIM, DIM);
    gemm_bf16_64<<<dim3(256 / 64, MROWS / 64), 256, 0, stream>>>(xb, Wkvt, kv,
                                                                 DIM, 256);

    // RoPE + RMSNorm -> bf16
    rope_rms_bf16<<<dim3(MROWS * NH / 4), 256, 0, stream>>>(
        q, qb, cosb, sinb, NH, MROWS * NH, HD);
    rope_rms_bf16<<<dim3(MROWS / 4), 256, 0, stream>>>(
        kv, kb, cosb, sinb, 1, MROWS, 256);
    vtrans<<<dim3(LL / 64, 2, BB), 256, 0, stream>>>(kv + HD, vt, 256);

    // causal MQA attention (load-balanced q-strip pairs)
    flash_mfma<<<dim3(LL / 128, BB * NH), 256, 0, stream>>>(qb, kb, vt, aob);

    // output projection
    gemm_bf16<<<dim3(DIM / 128, MROWS / 128), 256, 0, stream>>>(aob, Wot, out,
                                                                DIM, DIM);
}